// Round 9
// baseline (282.089 us; speedup 1.0000x reference)
//
#include <hip/hip_runtime.h>
#include <math.h>

// SpectrumHead: rfft2(512x512) magnitude -> radial/angular histogram -> linear proj.
// B=64, C=3, H=512, W=512, W2=257 (padded to 272), K_BINS=16, O_BINS=8, proj=64.
//
// Both FFT passes use the three-step 512 = 8x8x8 register FFT with WAVE-PRIVATE
// LDS transposes: one 64-lane wave owns one 512-pt FFT inside its own LDS
// segment. Same-wave LDS ops execute in order on CDNA, so no __syncthreads is
// needed between transpose phases — only sched_barrier(0) to pin compiler
// ordering. XOR swizzle PH(i) = i ^ ((i>>6 & 7)<<3) makes every phase <=2
// lanes/bank-pair (free).
//
// Pass 0: bin-code table binsNat[row][j] = rb | ob<<4.
// Pass 1: row real-FFTs. Wave = one row-pair (2 real rows packed into one
//         complex FFT); contiguous rows -> coalesced 4B/lane loads, no staging.
//         1024-thr block = 16 FFTs, TWO __syncthreads total. Hermitian unpack
//         via in-segment Z round trip; block-cooperative coalesced F writes.
// Pass 2: column FFTs. Coalesced 16-col tile staged to LDS [col][PH(row)],
//         then wave w owns column w (wave-private FFT). 2 barriers/channel.
//         128-bin combined histogram, folded to 24.
// Pass 3: reduce tile-partials per batch, normalize, h @ W.T + b.
//
// LAUNCH BOUNDS CALIBRATION (empirical, this toolchain): reported VGPR cap
// ~= 256/arg2 (r3:3->80, r4/6:6->40, r7:8->32, r8:4->56 no-spill). Kernels
// need ~50 -> arg2=4 (cap 64).

#define TPB 256
#define TPB2 1024
#define PI_F 3.14159265358979323846f
#define TWO_PI_F 6.28318530717958647692f
#define W2 257
#define W2P 272            // padded row stride in float2
#define NTILE 17           // ceil(257/16): 16 columns per pass2 block
#define CS 529             // per-wave segment stride in float2 (>=514, ==17 mod 32)
#define PH(i) ((i) ^ ((((i) >> 6) & 7) << 3))   // in-segment anti-conflict swizzle
#define SB() __builtin_amdgcn_sched_barrier(0)

// exp(-2*pi*i*k/32), k = 0..15
static constexpr float TW32_RE[16] = {
   1.0f,          0.98078528f,  0.92387953f,  0.83146961f,
   0.70710678f,   0.55557023f,  0.38268343f,  0.19509032f,
   0.0f,         -0.19509032f, -0.38268343f, -0.55557023f,
  -0.70710678f,  -0.83146961f, -0.92387953f, -0.98078528f };
static constexpr float TW32_IM[16] = {
  -0.0f,         -0.19509032f, -0.38268343f, -0.55557023f,
  -0.70710678f,  -0.83146961f, -0.92387953f, -0.98078528f,
  -1.0f,         -0.98078528f, -0.92387953f, -0.83146961f,
  -0.70710678f,  -0.55557023f, -0.38268343f, -0.19509032f };

static constexpr int BR3[8] = {0,4,2,6,1,5,3,7};

__device__ __forceinline__ float2 cmulf(float2 a, float2 b) {
  return make_float2(a.x*b.x - a.y*b.y, a.x*b.y + a.y*b.x);
}

// In-register DIT FFT, N = 2^LOGN, twiddles from TW32 (k = jj<<(4-s)).
// Input bit-rev permuted; output natural order. Fully unrolled -> VGPRs.
template <int LOGN>
__device__ __forceinline__ void fft_reg(float2* z) {
  const int N = 1 << LOGN;
  #pragma unroll
  for (int s = 0; s < LOGN; ++s) {
    const int h = 1 << s;
    #pragma unroll
    for (int g0 = 0; g0 < N; g0 += 2 * h) {
      #pragma unroll
      for (int jj = 0; jj < h; ++jj) {
        const int k = jj << (4 - s);
        const float wr = TW32_RE[k], wi = TW32_IM[k];
        float2 a = z[g0 + jj];
        float2 b = z[g0 + jj + h];
        float tr = b.x * wr - b.y * wi;
        float ti = b.x * wi + b.y * wr;
        z[g0 + jj]     = make_float2(a.x + tr, a.y + ti);
        z[g0 + jj + h] = make_float2(a.x - tr, a.y - ti);
      }
    }
  }
}

__device__ __forceinline__ void get_bins(int i, int j, int& rb, int& ob) {
  float yy = -1.0f + (float)i * (2.0f / 511.0f);
  float xx = (float)j * (1.0f / 256.0f);
  float rr = sqrtf(yy * yy + xx * xx);
  rr = fminf(rr, 1.0f - 1e-8f);
  float th = atan2f(yy, xx + 1e-9f) + 1.57079632679489662f;
  rb = (int)(rr * 16.0f);
  rb = rb < 0 ? 0 : (rb > 15 ? 15 : rb);
  ob = (int)((th / PI_F) * 8.0f);
  ob = ob < 0 ? 0 : (ob > 7 ? 7 : ob);
}

// Pass 0: bin table, natural row order. blockIdx.x = row i.
__global__ __launch_bounds__(TPB) void pass0_kernel(unsigned char* __restrict__ binsNat) {
  int i = blockIdx.x;
  #pragma unroll
  for (int e = 0; e < 2; e++) {
    int j = threadIdx.x + e * 256;
    if (j < W2) {
      int rb, ob;
      get_bins(i, j, rb, ob);
      binsNat[i * W2P + j] = (unsigned char)(rb | (ob << 4));
    }
  }
}

// Pass 1: blockIdx.x = ic_local*16 + segblk. Wave wv handles row-pair
// rp = segblk*16 + wv (rows 2rp, 2rp+1 packed as one complex 512-pt FFT).
__global__ __launch_bounds__(TPB2, 4) void pass1_kernel(
    const float* __restrict__ x, float2* __restrict__ F, int ic0) {
  __shared__ float2 xbuf[16 * CS];       // 16 wave-private segments
  __shared__ float2 tw512[512];
  int t = threadIdx.x;
  int segblk = blockIdx.x & 15;
  int ic_local = blockIdx.x >> 4;
  int wv = t >> 6;                       // wave id = row-pair slot
  int u = t & 63;                        // lane
  int rp = segblk * 16 + wv;
  const float* row0 = x + (((size_t)(ic0 + ic_local)) * 512 + (size_t)rp * 2) * 512;
  const float* row1 = row0 + 512;
  float2* seg = xbuf + wv * CS;
  float2* Fimg = F + (size_t)ic_local * (512 * W2P);

  if (t < 512) {
    float sn, cs;
    sincosf(-TWO_PI_F * (float)t * (1.0f / 512.0f), &sn, &cs);
    tw512[t] = make_float2(cs, sn);
  }
  __syncthreads();

  const int ul = u & 7, wq = u >> 3;

  // step 1: FFT8 over m (elems u + 64m), twiddle W_512^(u*k3)
  float2 z[8];
  #pragma unroll
  for (int m = 0; m < 8; ++m)
    z[BR3[m]] = make_float2(row0[u + 64 * m], row1[u + 64 * m]);
  fft_reg<3>(z);
  #pragma unroll
  for (int k3 = 0; k3 < 8; ++k3) z[k3] = cmulf(z[k3], tw512[u * k3]);
  SB();
  #pragma unroll
  for (int k3 = 0; k3 < 8; ++k3) seg[PH(k3 * 64 + u)] = z[k3];   // L1[k3][u]
  SB();
  // step 2: FFT8 over g2, twiddle W_64^(g1*K2)
  float2 r[8];
  #pragma unroll
  for (int g2 = 0; g2 < 8; ++g2) r[BR3[g2]] = seg[PH(wq * 64 + ul + 8 * g2)];
  fft_reg<3>(r);
  #pragma unroll
  for (int K2 = 0; K2 < 8; ++K2) r[K2] = cmulf(r[K2], tw512[(ul * K2) << 3]);
  SB();
  #pragma unroll
  for (int K2 = 0; K2 < 8; ++K2) seg[PH(wq * 64 + K2 * 8 + ul)] = r[K2];  // L2
  SB();
  // step 3: FFT8 over g1 -> Z[k], k = wq + 8*ul + 64*K1
  float2 s[8];
  #pragma unroll
  for (int gg = 0; gg < 8; ++gg) s[BR3[gg]] = seg[PH(wq * 64 + ul * 8 + gg)];
  fft_reg<3>(s);
  SB();
  #pragma unroll
  for (int K1 = 0; K1 < 8; ++K1) seg[PH(wq + 8 * ul + 64 * K1)] = s[K1];  // Z natural
  SB();
  // Hermitian unpack: k = u + 64e (e<4) + (k=256 on lane 0). All reads issue
  // before any write (lockstep + in-order LDS), then overwrite segment with
  // F0 at [k], F1 at [257+k] (unswizzled).
  float2 f0[4], f1[4];
  float2 f0n = make_float2(0.0f, 0.0f), f1n = make_float2(0.0f, 0.0f);
  #pragma unroll
  for (int e = 0; e < 4; ++e) {
    int k = u + 64 * e;
    int km = (512 - k) & 511;
    float2 zk = seg[PH(k)];
    float2 zm = seg[PH(km)];
    f0[e] = make_float2(0.5f * (zk.x + zm.x), 0.5f * (zk.y - zm.y));
    f1[e] = make_float2(0.5f * (zk.y + zm.y), -0.5f * (zk.x - zm.x));
  }
  if (u == 0) {
    float2 zk = seg[PH(256)];             // Nyquist (self-paired)
    f0n = make_float2(zk.x, 0.0f);
    f1n = make_float2(zk.y, 0.0f);
  }
  SB();
  #pragma unroll
  for (int e = 0; e < 4; ++e) {
    int k = u + 64 * e;
    seg[k] = f0[e];
    seg[257 + k] = f1[e];
  }
  if (u == 0) { seg[256] = f0n; seg[513] = f1n; }
  __syncthreads();

  // cooperative coalesced write-out: 16 pairs x 514 float2 (2056B runs)
  #pragma unroll
  for (int e2 = 0; e2 < 9; ++e2) {
    int idx = t + 1024 * e2;
    if (idx < 16 * 514) {
      int pair = idx / 514;
      int off = idx - pair * 514;
      int hi = (off >= 257) ? 1 : 0;
      int k = off - hi * 257;
      int row2 = (segblk * 16 + pair) * 2 + hi;
      Fimg[(size_t)row2 * W2P + k] = xbuf[pair * CS + off];
    }
  }
}

// Pass 2: blockIdx.x = b_local*NTILE + tile. Stage 16-col tile to LDS
// [col][PH(row)] (coalesced global), then wave wv owns column wv: the whole
// 8x8x8 FFT is wave-private in its segment. mag -> log1p -> 128-bin histogram.
__global__ __launch_bounds__(TPB2, 4) void pass2_kernel(
    const float2* __restrict__ F, const unsigned char* __restrict__ binsNat,
    float* __restrict__ partial, int b0) {
  __shared__ float2 xbuf[16 * CS];
  __shared__ float2 tw512[512];
  __shared__ float hist[128];            // combined bins: rb + 16*ob
  int t = threadIdx.x;
  int tile = blockIdx.x % NTILE;
  int b_local = blockIdx.x / NTILE;
  int wv = t >> 6;                       // wave id = column slot
  int u = t & 63;
  int scol = t & 15, srow = t >> 4;      // stage roles
  int jw = tile * 16 + wv;               // this wave's column (wave-uniform)
  bool jvalid = (jw < W2);
  int js = tile * 16 + scol;             // stage column
  bool svalid = (js < W2);
  float2* seg = xbuf + wv * CS;
  const float2* Fb = F + (size_t)(b_local * 3) * (512 * W2P);

  if (t < 512) {
    float sn, cs;
    sincosf(-TWO_PI_F * (float)t * (1.0f / 512.0f), &sn, &cs);
    tw512[t] = make_float2(cs, sn);
  }
  if (t < 128) hist[t] = 0.0f;
  __syncthreads();

  const int ul = u & 7, wq = u >> 3;

  float mag[8];
  #pragma unroll
  for (int q = 0; q < 8; ++q) mag[q] = 0.0f;

  for (int c = 0; c < 3; ++c) {
    const float2* Fc = Fb + (size_t)c * (512 * W2P);
    // stage: [512][16] tile -> segments (coalesced 128B global lines)
    #pragma unroll
    for (int e = 0; e < 8; ++e) {
      int row = e * 64 + srow;
      float2 v = svalid ? Fc[(size_t)row * W2P + js] : make_float2(0.0f, 0.0f);
      xbuf[scol * CS + PH(row)] = v;
    }
    __syncthreads();

    // wave-private 8x8x8 FFT on column jw
    float2 z[8];
    #pragma unroll
    for (int m = 0; m < 8; ++m) z[BR3[m]] = seg[PH(u + 64 * m)];
    fft_reg<3>(z);
    #pragma unroll
    for (int k3 = 0; k3 < 8; ++k3) z[k3] = cmulf(z[k3], tw512[u * k3]);
    SB();
    #pragma unroll
    for (int k3 = 0; k3 < 8; ++k3) seg[PH(k3 * 64 + u)] = z[k3];
    SB();
    float2 r[8];
    #pragma unroll
    for (int g2 = 0; g2 < 8; ++g2) r[BR3[g2]] = seg[PH(wq * 64 + ul + 8 * g2)];
    fft_reg<3>(r);
    #pragma unroll
    for (int K2 = 0; K2 < 8; ++K2) r[K2] = cmulf(r[K2], tw512[(ul * K2) << 3]);
    SB();
    #pragma unroll
    for (int K2 = 0; K2 < 8; ++K2) seg[PH(wq * 64 + K2 * 8 + ul)] = r[K2];
    SB();
    float2 s[8];
    #pragma unroll
    for (int gg = 0; gg < 8; ++gg) s[BR3[gg]] = seg[PH(wq * 64 + ul * 8 + gg)];
    fft_reg<3>(s);
    #pragma unroll
    for (int K1 = 0; K1 < 8; ++K1)
      mag[K1] += sqrtf(s[K1].x * s[K1].x + s[K1].y * s[K1].y);
    __syncthreads();                     // FFT reads done before next stage
  }

  if (jvalid) {
    #pragma unroll
    for (int K1 = 0; K1 < 8; ++K1) {
      int row = wq + 8 * ul + 64 * K1;
      int code = binsNat[row * W2P + jw];  // rb | ob<<4
      // scale: ortho (1/512) * channel mean (1/3) = 1/1536
      float m = log1pf(mag[K1] * (1.0f / 1536.0f));
      atomicAdd(&hist[code], m);
    }
  }
  __syncthreads();

  // fold 128 combined bins -> 16 radial + 8 angular partials
  int b = b0 + b_local;
  if (t < 16) {
    float s = 0.0f;
    #pragma unroll
    for (int ob = 0; ob < 8; ++ob) s += hist[t + 16 * ob];
    partial[((size_t)b * NTILE + tile) * 24 + t] = s;
  } else if (t < 24) {
    float s = 0.0f;
    int ob = t - 16;
    #pragma unroll
    for (int rb = 0; rb < 16; ++rb) s += hist[rb + 16 * ob];
    partial[((size_t)b * NTILE + tile) * 24 + t] = s;
  }
}

// Pass 3: one block per batch. Reduce NTILE partials, normalize, project.
__global__ __launch_bounds__(TPB) void pass3_kernel(
    const float* __restrict__ partial, const float* __restrict__ W,
    const float* __restrict__ bias, float* __restrict__ out) {
  __shared__ float h[24];
  __shared__ float hn[24];
  int b = blockIdx.x;
  int t = threadIdx.x;
  if (t < 24) {
    float s = 0.0f;
    for (int tile = 0; tile < NTILE; tile++)
      s += partial[((size_t)b * NTILE + tile) * 24 + t];
    h[t] = s;
  }
  __syncthreads();
  if (t == 0) {
    float rs = 0.0f, as = 0.0f;
    for (int k = 0; k < 16; k++) rs += h[k];
    for (int k = 16; k < 24; k++) as += h[k];
    for (int k = 0; k < 16; k++) hn[k] = h[k] / (rs + 1e-6f);
    for (int k = 16; k < 24; k++) hn[k] = h[k] / (as + 1e-6f);
  }
  __syncthreads();
  if (t < 64) {
    float acc = bias[t];
    #pragma unroll
    for (int k = 0; k < 24; k++) acc += hn[k] * W[t * 24 + k];
    out[b * 64 + t] = acc;
  }
}

extern "C" void kernel_launch(void* const* d_in, const int* in_sizes, int n_in,
                              void* d_out, int out_size, void* d_ws, size_t ws_size,
                              hipStream_t stream) {
  const float* x    = (const float*)d_in[0];   // [64,3,512,512]
  const float* W    = (const float*)d_in[1];   // [64,24]
  const float* bias = (const float*)d_in[2];   // [64]
  float* out = (float*)d_out;                  // [64,64]

  // ws layout: partial hists | bin table | complex intermediate F
  const size_t partial_bytes = (size_t)64 * NTILE * 24 * sizeof(float);
  size_t off_bins = (partial_bytes + 255) & ~(size_t)255;
  const size_t bins_bytes = (size_t)512 * W2P;
  size_t off_F = ((off_bins + bins_bytes) + 255) & ~(size_t)255;

  float* partial = (float*)d_ws;
  unsigned char* binsNat = (unsigned char*)d_ws + off_bins;
  float2* F = (float2*)((char*)d_ws + off_F);

  const size_t per_batch = (size_t)3 * 512 * W2P * sizeof(float2);  // 3.34 MB
  size_t avail = ws_size > off_F ? ws_size - off_F : 0;
  int bpc = (int)(avail / per_batch);
  if (bpc < 1) bpc = 1;
  if (bpc > 64) bpc = 64;

  pass0_kernel<<<512, TPB, 0, stream>>>(binsNat);

  for (int b0 = 0; b0 < 64; b0 += bpc) {
    int nb = (64 - b0) < bpc ? (64 - b0) : bpc;
    pass1_kernel<<<nb * 3 * 16, TPB2, 0, stream>>>(x, F, b0 * 3);
    pass2_kernel<<<nb * NTILE, TPB2, 0, stream>>>(F, binsNat, partial, b0);
  }
  pass3_kernel<<<64, TPB, 0, stream>>>(partial, W, bias, out);
}

// Round 10
// 258.030 us; speedup vs baseline: 1.0932x; 1.0932x over previous
//
#include <hip/hip_runtime.h>
#include <math.h>

// SpectrumHead: rfft2(512x512) magnitude -> radial/angular histogram -> linear proj.
// B=64, C=3, H=512, W=512, W2=257 (padded to 272), K_BINS=16, O_BINS=8, proj=64.
//
// Three-step 512 = 8x8x8 register FFT, wave-private LDS segments (no barriers
// between transpose phases; same-wave LDS ops are in-order).
//
// SWIZZLE (bank-exact): PH(i) = i ^ 9*(i>>6 & 7)  — injects the high octave q
// into BOTH bits 0-2 and 3-5. Per-phase bank math (b64 fp32 pass1 / b32 bf16
// pass2) puts every FFT phase at the wave64 LDS floor. (r9's (q<<3)-only
// swizzle left step-3 reads at 4x floor -> 8.1e6 conflicts.)
//
// Pass 1: row real-FFTs, wave = one row-pair, TPB 512 (8 pairs, fp32 segments,
//         37.9 KB -> 4 blocks/CU). Hermitian unpack in-segment; coalesced F write.
// Pass 2: column FFTs. 16-col tile staged (coalesced 128B) into 16 bf16-packed
//         segments (truncation pack; ~0.5% rel on X, ~1e-4 at output vs 2.77e-3
//         threshold; normalization cancels common-mode bias). TPB 512, wave wv
//         owns cols {wv, wv+8}; 37.4 KB LDS -> 4 desynced blocks/CU.
// Pass 3: reduce tile-partials, normalize, h @ W.T + b.
//
// LAUNCH BOUNDS CALIBRATION (empirical): reported VGPR cap ~= 256/arg2
// (r3:3->80, r4/6:6->40, r7:8->32, r8:4->56). arg2=4 -> cap 64.

#define TPB 256
#define TPB2 512
#define PI_F 3.14159265358979323846f
#define TWO_PI_F 6.28318530717958647692f
#define W2 257
#define W2P 272            // padded row stride in float2 (and bytes for bin table)
#define NTILE 17           // ceil(257/16): 16 columns per pass2 block
#define CS 529             // pass1 per-wave segment stride, float2 units
#define CSB 513            // pass2 per-col segment stride, uint32 units (==1 mod 32)
#define PH(i) ((i) ^ ((((i) >> 6) & 7) * 9))   // anti-conflict swizzle (mult 9)
#define SB() __builtin_amdgcn_sched_barrier(0)

// exp(-2*pi*i*k/32), k = 0..15
static constexpr float TW32_RE[16] = {
   1.0f,          0.98078528f,  0.92387953f,  0.83146961f,
   0.70710678f,   0.55557023f,  0.38268343f,  0.19509032f,
   0.0f,         -0.19509032f, -0.38268343f, -0.55557023f,
  -0.70710678f,  -0.83146961f, -0.92387953f, -0.98078528f };
static constexpr float TW32_IM[16] = {
  -0.0f,         -0.19509032f, -0.38268343f, -0.55557023f,
  -0.70710678f,  -0.83146961f, -0.92387953f, -0.98078528f,
  -1.0f,         -0.98078528f, -0.92387953f, -0.83146961f,
  -0.70710678f,  -0.55557023f, -0.38268343f, -0.19509032f };

static constexpr int BR3[8] = {0,4,2,6,1,5,3,7};

__device__ __forceinline__ float2 cmulf(float2 a, float2 b) {
  return make_float2(a.x*b.x - a.y*b.y, a.x*b.y + a.y*b.x);
}

__device__ __forceinline__ unsigned bfpack(float2 v) {
  unsigned a = __float_as_uint(v.x) >> 16;
  unsigned b = __float_as_uint(v.y) & 0xFFFF0000u;
  return b | a;
}
__device__ __forceinline__ float2 bfunpack(unsigned p) {
  return make_float2(__uint_as_float(p << 16), __uint_as_float(p & 0xFFFF0000u));
}

// In-register DIT FFT, N = 2^LOGN, twiddles from TW32 (k = jj<<(4-s)).
// Input bit-rev permuted; output natural order. Fully unrolled -> VGPRs.
template <int LOGN>
__device__ __forceinline__ void fft_reg(float2* z) {
  const int N = 1 << LOGN;
  #pragma unroll
  for (int s = 0; s < LOGN; ++s) {
    const int h = 1 << s;
    #pragma unroll
    for (int g0 = 0; g0 < N; g0 += 2 * h) {
      #pragma unroll
      for (int jj = 0; jj < h; ++jj) {
        const int k = jj << (4 - s);
        const float wr = TW32_RE[k], wi = TW32_IM[k];
        float2 a = z[g0 + jj];
        float2 b = z[g0 + jj + h];
        float tr = b.x * wr - b.y * wi;
        float ti = b.x * wi + b.y * wr;
        z[g0 + jj]     = make_float2(a.x + tr, a.y + ti);
        z[g0 + jj + h] = make_float2(a.x - tr, a.y - ti);
      }
    }
  }
}

__device__ __forceinline__ void get_bins(int i, int j, int& rb, int& ob) {
  float yy = -1.0f + (float)i * (2.0f / 511.0f);
  float xx = (float)j * (1.0f / 256.0f);
  float rr = sqrtf(yy * yy + xx * xx);
  rr = fminf(rr, 1.0f - 1e-8f);
  float th = atan2f(yy, xx + 1e-9f) + 1.57079632679489662f;
  rb = (int)(rr * 16.0f);
  rb = rb < 0 ? 0 : (rb > 15 ? 15 : rb);
  ob = (int)((th / PI_F) * 8.0f);
  ob = ob < 0 ? 0 : (ob > 7 ? 7 : ob);
}

// Pass 0: bin table, natural row order. blockIdx.x = row i.
__global__ __launch_bounds__(TPB) void pass0_kernel(unsigned char* __restrict__ binsNat) {
  int i = blockIdx.x;
  #pragma unroll
  for (int e = 0; e < 2; e++) {
    int j = threadIdx.x + e * 256;
    if (j < W2) {
      int rb, ob;
      get_bins(i, j, rb, ob);
      binsNat[i * W2P + j] = (unsigned char)(rb | (ob << 4));
    }
  }
}

// Pass 1: blockIdx.x = ic_local*32 + segblk. Wave wv handles row-pair
// rp = segblk*8 + wv (rows 2rp, 2rp+1 packed as one complex 512-pt FFT).
__global__ __launch_bounds__(TPB2, 4) void pass1_kernel(
    const float* __restrict__ x, float2* __restrict__ F, int ic0) {
  __shared__ float2 xbuf[8 * CS];        // 8 wave-private fp32 segments
  __shared__ float2 tw512[512];
  int t = threadIdx.x;
  int segblk = blockIdx.x & 31;
  int ic_local = blockIdx.x >> 5;
  int wv = t >> 6;                       // wave id = row-pair slot (0..7)
  int u = t & 63;                        // lane
  int rp = segblk * 8 + wv;
  const float* row0 = x + (((size_t)(ic0 + ic_local)) * 512 + (size_t)rp * 2) * 512;
  const float* row1 = row0 + 512;
  float2* seg = xbuf + wv * CS;
  float2* Fimg = F + (size_t)ic_local * (512 * W2P);

  {
    float sn, cs;
    sincosf(-TWO_PI_F * (float)t * (1.0f / 512.0f), &sn, &cs);
    tw512[t] = make_float2(cs, sn);
  }
  __syncthreads();

  const int ul = u & 7, wq = u >> 3;

  // step 1: FFT8 over m (elems u + 64m), twiddle W_512^(u*k3)
  float2 z[8];
  #pragma unroll
  for (int m = 0; m < 8; ++m)
    z[BR3[m]] = make_float2(row0[u + 64 * m], row1[u + 64 * m]);
  fft_reg<3>(z);
  #pragma unroll
  for (int k3 = 0; k3 < 8; ++k3) z[k3] = cmulf(z[k3], tw512[u * k3]);
  SB();
  #pragma unroll
  for (int k3 = 0; k3 < 8; ++k3) seg[PH(k3 * 64 + u)] = z[k3];   // L1[k3][u]
  SB();
  // step 2: FFT8 over g2, twiddle W_64^(g1*K2)
  #pragma unroll
  for (int g2 = 0; g2 < 8; ++g2) z[BR3[g2]] = seg[PH(wq * 64 + ul + 8 * g2)];
  fft_reg<3>(z);
  #pragma unroll
  for (int K2 = 0; K2 < 8; ++K2) z[K2] = cmulf(z[K2], tw512[(ul * K2) << 3]);
  SB();
  #pragma unroll
  for (int K2 = 0; K2 < 8; ++K2) seg[PH(wq * 64 + K2 * 8 + ul)] = z[K2];  // L2
  SB();
  // step 3: FFT8 over g1 -> Z[k], k = wq + 8*ul + 64*K1
  #pragma unroll
  for (int gg = 0; gg < 8; ++gg) z[BR3[gg]] = seg[PH(wq * 64 + ul * 8 + gg)];
  fft_reg<3>(z);
  SB();
  #pragma unroll
  for (int K1 = 0; K1 < 8; ++K1) seg[PH(wq + 8 * ul + 64 * K1)] = z[K1];  // Z natural
  SB();
  // Hermitian unpack: all reads before any write (in-order wave LDS), then
  // overwrite segment with F0 at [k], F1 at [257+k] (unswizzled).
  float2 f0[4], f1[4];
  float2 f0n = make_float2(0.0f, 0.0f), f1n = make_float2(0.0f, 0.0f);
  #pragma unroll
  for (int e = 0; e < 4; ++e) {
    int k = u + 64 * e;
    int km = (512 - k) & 511;
    float2 zk = seg[PH(k)];
    float2 zm = seg[PH(km)];
    f0[e] = make_float2(0.5f * (zk.x + zm.x), 0.5f * (zk.y - zm.y));
    f1[e] = make_float2(0.5f * (zk.y + zm.y), -0.5f * (zk.x - zm.x));
  }
  if (u == 0) {
    float2 zk = seg[PH(256)];             // Nyquist (self-paired)
    f0n = make_float2(zk.x, 0.0f);
    f1n = make_float2(zk.y, 0.0f);
  }
  SB();
  #pragma unroll
  for (int e = 0; e < 4; ++e) {
    int k = u + 64 * e;
    seg[k] = f0[e];
    seg[257 + k] = f1[e];
  }
  if (u == 0) { seg[256] = f0n; seg[513] = f1n; }
  __syncthreads();

  // cooperative coalesced write-out: 8 pairs x 514 float2 (2056B runs)
  #pragma unroll
  for (int e2 = 0; e2 < 9; ++e2) {
    int idx = t + TPB2 * e2;
    if (idx < 8 * 514) {
      int pair = idx / 514;
      int off = idx - pair * 514;
      int hi = (off >= 257) ? 1 : 0;
      int k = off - hi * 257;
      int row2 = (segblk * 8 + pair) * 2 + hi;
      Fimg[(size_t)row2 * W2P + k] = xbuf[pair * CS + off];
    }
  }
}

// Wave-private 8x8x8 column FFT on a bf16-packed segment; accumulates |X| into
// mag[K1] for rows wq + 8*ul + 64*K1.
__device__ __forceinline__ void fft_col_512(unsigned* seg, int u,
                                            const float2* tw512, float* mag) {
  const int ul = u & 7, wq = u >> 3;
  float2 z[8];
  #pragma unroll
  for (int m = 0; m < 8; ++m) z[BR3[m]] = bfunpack(seg[PH(u + 64 * m)]);
  fft_reg<3>(z);
  #pragma unroll
  for (int k3 = 0; k3 < 8; ++k3) z[k3] = cmulf(z[k3], tw512[u * k3]);
  SB();
  #pragma unroll
  for (int k3 = 0; k3 < 8; ++k3) seg[PH(k3 * 64 + u)] = bfpack(z[k3]);
  SB();
  #pragma unroll
  for (int g2 = 0; g2 < 8; ++g2) z[BR3[g2]] = bfunpack(seg[PH(wq * 64 + ul + 8 * g2)]);
  fft_reg<3>(z);
  #pragma unroll
  for (int K2 = 0; K2 < 8; ++K2) z[K2] = cmulf(z[K2], tw512[(ul * K2) << 3]);
  SB();
  #pragma unroll
  for (int K2 = 0; K2 < 8; ++K2) seg[PH(wq * 64 + K2 * 8 + ul)] = bfpack(z[K2]);
  SB();
  #pragma unroll
  for (int gg = 0; gg < 8; ++gg) z[BR3[gg]] = bfunpack(seg[PH(wq * 64 + ul * 8 + gg)]);
  fft_reg<3>(z);
  #pragma unroll
  for (int K1 = 0; K1 < 8; ++K1)
    mag[K1] += sqrtf(z[K1].x * z[K1].x + z[K1].y * z[K1].y);
}

// Pass 2: blockIdx.x = b_local*NTILE + tile. Stage 16-col tile (coalesced,
// bf16-packed) into 16 segments; wave wv owns columns wv and wv+8.
__global__ __launch_bounds__(TPB2, 4) void pass2_kernel(
    const float2* __restrict__ F, const unsigned char* __restrict__ binsNat,
    float* __restrict__ partial, int b0) {
  __shared__ unsigned xbuf[16 * CSB];    // 32.8 KB bf16-packed segments
  __shared__ float2 tw512[512];
  __shared__ float hist[128];            // combined bins: rb + 16*ob
  int t = threadIdx.x;
  int tile = blockIdx.x % NTILE;
  int b_local = blockIdx.x / NTILE;
  int wv = t >> 6;                       // wave id (0..7)
  int u = t & 63;
  int scol = t & 15, srow = t >> 4;      // stage roles (srow 0..31)
  int jA = tile * 16 + wv;               // wave's first column
  int jB = jA + 8;                       // wave's second column
  bool validA = (jA < W2), validB = (jB < W2);
  int js = tile * 16 + scol;
  bool svalid = (js < W2);
  unsigned* segA = xbuf + wv * CSB;
  unsigned* segB = xbuf + (wv + 8) * CSB;
  const float2* Fb = F + (size_t)(b_local * 3) * (512 * W2P);

  {
    float sn, cs;
    sincosf(-TWO_PI_F * (float)t * (1.0f / 512.0f), &sn, &cs);
    tw512[t] = make_float2(cs, sn);
  }
  if (t < 128) hist[t] = 0.0f;

  const int ul = u & 7, wq = u >> 3;

  float magA[8], magB[8];
  #pragma unroll
  for (int q = 0; q < 8; ++q) { magA[q] = 0.0f; magB[q] = 0.0f; }

  for (int c = 0; c < 3; ++c) {
    const float2* Fc = Fb + (size_t)c * (512 * W2P);
    __syncthreads();                     // prev FFT reads done (and init, c=0)
    #pragma unroll 4
    for (int e = 0; e < 16; ++e) {
      int row = srow + 32 * e;
      float2 v = svalid ? Fc[(size_t)row * W2P + js] : make_float2(0.0f, 0.0f);
      xbuf[scol * CSB + PH(row)] = bfpack(v);
    }
    __syncthreads();
    fft_col_512(segA, u, tw512, magA);
    fft_col_512(segB, u, tw512, magB);
  }

  if (validA) {
    #pragma unroll
    for (int K1 = 0; K1 < 8; ++K1) {
      int row = wq + 8 * ul + 64 * K1;
      int code = binsNat[row * W2P + jA];
      // scale: ortho (1/512) * channel mean (1/3) = 1/1536
      atomicAdd(&hist[code], log1pf(magA[K1] * (1.0f / 1536.0f)));
    }
  }
  if (validB) {
    #pragma unroll
    for (int K1 = 0; K1 < 8; ++K1) {
      int row = wq + 8 * ul + 64 * K1;
      int code = binsNat[row * W2P + jB];
      atomicAdd(&hist[code], log1pf(magB[K1] * (1.0f / 1536.0f)));
    }
  }
  __syncthreads();

  // fold 128 combined bins -> 16 radial + 8 angular partials
  int b = b0 + b_local;
  if (t < 16) {
    float s = 0.0f;
    #pragma unroll
    for (int ob = 0; ob < 8; ++ob) s += hist[t + 16 * ob];
    partial[((size_t)b * NTILE + tile) * 24 + t] = s;
  } else if (t < 24) {
    float s = 0.0f;
    int ob = t - 16;
    #pragma unroll
    for (int rb = 0; rb < 16; ++rb) s += hist[rb + 16 * ob];
    partial[((size_t)b * NTILE + tile) * 24 + t] = s;
  }
}

// Pass 3: one block per batch. Reduce NTILE partials, normalize, project.
__global__ __launch_bounds__(TPB) void pass3_kernel(
    const float* __restrict__ partial, const float* __restrict__ W,
    const float* __restrict__ bias, float* __restrict__ out) {
  __shared__ float h[24];
  __shared__ float hn[24];
  int b = blockIdx.x;
  int t = threadIdx.x;
  if (t < 24) {
    float s = 0.0f;
    for (int tile = 0; tile < NTILE; tile++)
      s += partial[((size_t)b * NTILE + tile) * 24 + t];
    h[t] = s;
  }
  __syncthreads();
  if (t == 0) {
    float rs = 0.0f, as = 0.0f;
    for (int k = 0; k < 16; k++) rs += h[k];
    for (int k = 16; k < 24; k++) as += h[k];
    for (int k = 0; k < 16; k++) hn[k] = h[k] / (rs + 1e-6f);
    for (int k = 16; k < 24; k++) hn[k] = h[k] / (as + 1e-6f);
  }
  __syncthreads();
  if (t < 64) {
    float acc = bias[t];
    #pragma unroll
    for (int k = 0; k < 24; k++) acc += hn[k] * W[t * 24 + k];
    out[b * 64 + t] = acc;
  }
}

extern "C" void kernel_launch(void* const* d_in, const int* in_sizes, int n_in,
                              void* d_out, int out_size, void* d_ws, size_t ws_size,
                              hipStream_t stream) {
  const float* x    = (const float*)d_in[0];   // [64,3,512,512]
  const float* W    = (const float*)d_in[1];   // [64,24]
  const float* bias = (const float*)d_in[2];   // [64]
  float* out = (float*)d_out;                  // [64,64]

  // ws layout: partial hists | bin table | complex intermediate F
  const size_t partial_bytes = (size_t)64 * NTILE * 24 * sizeof(float);
  size_t off_bins = (partial_bytes + 255) & ~(size_t)255;
  const size_t bins_bytes = (size_t)512 * W2P;
  size_t off_F = ((off_bins + bins_bytes) + 255) & ~(size_t)255;

  float* partial = (float*)d_ws;
  unsigned char* binsNat = (unsigned char*)d_ws + off_bins;
  float2* F = (float2*)((char*)d_ws + off_F);

  const size_t per_batch = (size_t)3 * 512 * W2P * sizeof(float2);  // 3.34 MB
  size_t avail = ws_size > off_F ? ws_size - off_F : 0;
  int bpc = (int)(avail / per_batch);
  if (bpc < 1) bpc = 1;
  if (bpc > 64) bpc = 64;

  pass0_kernel<<<512, TPB, 0, stream>>>(binsNat);

  for (int b0 = 0; b0 < 64; b0 += bpc) {
    int nb = (64 - b0) < bpc ? (64 - b0) : bpc;
    pass1_kernel<<<nb * 3 * 32, TPB2, 0, stream>>>(x, F, b0 * 3);
    pass2_kernel<<<nb * NTILE, TPB2, 0, stream>>>(F, binsNat, partial, b0);
  }
  pass3_kernel<<<64, TPB, 0, stream>>>(partial, W, bias, out);
}

// Round 11
// 177.247 us; speedup vs baseline: 1.5915x; 1.4558x over previous
//
#include <hip/hip_runtime.h>
#include <math.h>

// SpectrumHead: rfft2(512x512) magnitude -> radial/angular histogram -> linear proj.
// B=64, C=3, H=512, W=512, W2=257, K_BINS=16, O_BINS=8, proj=64.
//
// Three-step 512 = 8x8x8 register FFT in WAVE-PRIVATE LDS segments (same-wave
// LDS ops are in-order on CDNA -> no barriers between transpose phases; only
// sched_barrier(0) pins compiler order). Swizzle PH(i) = i ^ 9*(i>>6&7), written
// in folded form (C ^ 9q) + 64q so each address is one XOR. All FFT phases are
// at the wave64 LDS bank floor (verified per-phase mod-32 arithmetic).
//
// F intermediate is stored TRANSPOSED and bf16-packed: FT[ch_img][j][i] (uint32
// per complex). This makes pass2 column loads contiguous 2KB runs -> pass2 needs
// NO cross-wave staging at all (zero barriers except histogram init/fold).
// bf16 pack costs no extra precision vs r10 (same values were packed to bf16 in
// LDS before); pass1 internal math stays fp32.
//
// Pass 0: transposed bin table binsT[j][i] (coalesced for pass2).
// Pass 1: TPB 1024 (16 waves = 16 row-pairs = 32 rows). Wave-private FFT +
//         Hermitian unpack + bf16 pack into own segment; ONE barrier; block
//         transposed write-out in 128B i-chunks per j.
// Pass 2: TPB 256, wave = one column j. 3 channels x (contiguous load + wave-
//         private FFT) -> mags -> log1p -> 128-bin LDS hist -> fold to 24.
// Pass 3: reduce tile-partials, normalize, h @ W.T + b.
//
// Twiddles: no LDS tables. Per thread: w1 = W512^-u, w64 = W64^-ul via one
// sincosf each; per call, chained powers (fp32 chain error ~1e-7, negligible).
//
// LAUNCH BOUNDS CALIBRATION (empirical, this toolchain): reported VGPR cap
// ~= 256/arg2 (r3:3->80, r4/6:6->40, r7:8->32, r8:4->56 no-spill). arg2=4 ->
// cap 64; both FFT kernels need ~50.

#define TPB0 256
#define TPB1 1024
#define TPB2 256
#define W2 257
#define NTILE 65           // pass2: 4 columns per block
#define CS 529             // pass1 per-wave segment stride, float2 units
#define CSU (2*CS)         // same stride in uint units (1058)
#define CSB 513            // pass2 per-wave segment stride, uint units
#define FTS 512            // FT row stride in uints (2KB rows, line-aligned)
#define PI_F 3.14159265358979323846f
#define TWO_PI_F 6.28318530717958647692f
#define SB() __builtin_amdgcn_sched_barrier(0)
#define PH(i) ((i) ^ ((((i) >> 6) & 7) * 9))

// exp(-2*pi*i*k/32), k = 0..15
static constexpr float TW32_RE[16] = {
   1.0f,          0.98078528f,  0.92387953f,  0.83146961f,
   0.70710678f,   0.55557023f,  0.38268343f,  0.19509032f,
   0.0f,         -0.19509032f, -0.38268343f, -0.55557023f,
  -0.70710678f,  -0.83146961f, -0.92387953f, -0.98078528f };
static constexpr float TW32_IM[16] = {
  -0.0f,         -0.19509032f, -0.38268343f, -0.55557023f,
  -0.70710678f,  -0.83146961f, -0.92387953f, -0.98078528f,
  -1.0f,         -0.98078528f, -0.92387953f, -0.83146961f,
  -0.70710678f,  -0.55557023f, -0.38268343f, -0.19509032f };

static constexpr int BR3[8] = {0,4,2,6,1,5,3,7};

__device__ __forceinline__ float2 cmulf(float2 a, float2 b) {
  return make_float2(a.x*b.x - a.y*b.y, a.x*b.y + a.y*b.x);
}
__device__ __forceinline__ unsigned bfpack(float2 v) {
  unsigned a = __float_as_uint(v.x) >> 16;
  unsigned b = __float_as_uint(v.y) & 0xFFFF0000u;
  return b | a;
}
__device__ __forceinline__ float2 bfunpack(unsigned p) {
  return make_float2(__uint_as_float(p << 16), __uint_as_float(p & 0xFFFF0000u));
}

// In-register DIT FFT8, twiddles from TW32. Input bit-rev permuted; output
// natural. Fully unrolled -> VGPRs.
template <int LOGN>
__device__ __forceinline__ void fft_reg(float2* z) {
  const int N = 1 << LOGN;
  #pragma unroll
  for (int s = 0; s < LOGN; ++s) {
    const int h = 1 << s;
    #pragma unroll
    for (int g0 = 0; g0 < N; g0 += 2 * h) {
      #pragma unroll
      for (int jj = 0; jj < h; ++jj) {
        const int k = jj << (4 - s);
        const float wr = TW32_RE[k], wi = TW32_IM[k];
        float2 a = z[g0 + jj];
        float2 b = z[g0 + jj + h];
        float tr = b.x * wr - b.y * wi;
        float ti = b.x * wi + b.y * wr;
        z[g0 + jj]     = make_float2(a.x + tr, a.y + ti);
        z[g0 + jj + h] = make_float2(a.x - tr, a.y - ti);
      }
    }
  }
}

// Apply chained twiddle powers: z[k] *= base^k, k = 1..7.
__device__ __forceinline__ void twiddle_chain(float2* z, float2 base) {
  float2 wk = base;
  #pragma unroll
  for (int k = 1; k < 8; ++k) {
    z[k] = cmulf(z[k], wk);
    if (k < 7) wk = cmulf(wk, base);
  }
}

__device__ __forceinline__ void get_bins(int i, int j, int& rb, int& ob) {
  float yy = -1.0f + (float)i * (2.0f / 511.0f);
  float xx = (float)j * (1.0f / 256.0f);
  float rr = sqrtf(yy * yy + xx * xx);
  rr = fminf(rr, 1.0f - 1e-8f);
  float th = atan2f(yy, xx + 1e-9f) + 1.57079632679489662f;
  rb = (int)(rr * 16.0f);
  rb = rb < 0 ? 0 : (rb > 15 ? 15 : rb);
  ob = (int)((th / PI_F) * 8.0f);
  ob = ob < 0 ? 0 : (ob > 7 ? 7 : ob);
}

// Pass 0: TRANSPOSED bin table binsT[j][i] = rb | ob<<4. blockIdx.x = j.
__global__ __launch_bounds__(TPB0) void pass0_kernel(unsigned char* __restrict__ binsT) {
  int j = blockIdx.x;           // 0..256
  #pragma unroll
  for (int e = 0; e < 2; e++) {
    int i = threadIdx.x + e * 256;
    int rb, ob;
    get_bins(i, j, rb, ob);
    binsT[(size_t)j * 512 + i] = (unsigned char)(rb | (ob << 4));
  }
}

// Pass 1: blockIdx.x = ic_local*16 + segblk. Wave wv = row-pair
// rp = segblk*16 + wv (rows 2rp, 2rp+1 packed as one complex 512-pt FFT).
// Output: FT[ic_local][j][i] bf16-packed, i-chunk [segblk*32, +32).
__global__ __launch_bounds__(TPB1, 4) void pass1_kernel(
    const float* __restrict__ x, unsigned* __restrict__ FT, int ic0) {
  __shared__ float2 xbuf[16 * CS];       // 67.7 KB: 16 wave-private segments
  int t = threadIdx.x;
  int segblk = blockIdx.x & 15;
  int ic_local = blockIdx.x >> 4;
  int wv = t >> 6;
  int u = t & 63;
  int rp = segblk * 16 + wv;
  const float* row0 = x + (((size_t)(ic0 + ic_local)) * 512 + (size_t)rp * 2) * 512;
  const float* row1 = row0 + 512;
  float2* seg = xbuf + wv * CS;
  unsigned* useg = (unsigned*)xbuf + wv * CSU;

  const int ul = u & 7, wq = u >> 3;
  const int x9 = 9 * wq, b64 = 64 * wq;

  float2 w1, w64;
  { float sn, cs;
    sincosf(-TWO_PI_F * (float)u * (1.0f / 512.0f), &sn, &cs);  w1  = make_float2(cs, sn);
    sincosf(-TWO_PI_F * (float)ul * (1.0f / 64.0f), &sn, &cs);  w64 = make_float2(cs, sn); }

  // step 1: FFT8 over m, twiddle W512^(u*k3) via chain
  float2 z[8];
  #pragma unroll
  for (int m = 0; m < 8; ++m)
    z[BR3[m]] = make_float2(row0[u + 64 * m], row1[u + 64 * m]);
  fft_reg<3>(z);
  twiddle_chain(z, w1);
  SB();
  #pragma unroll
  for (int k3 = 0; k3 < 8; ++k3) seg[(u ^ (9 * k3)) + 64 * k3] = z[k3];   // L1[k3][u]
  SB();
  // step 2: FFT8 over g2, twiddle W64^(ul*K2) via chain
  #pragma unroll
  for (int g2 = 0; g2 < 8; ++g2) z[BR3[g2]] = seg[((ul + 8 * g2) ^ x9) + b64];
  fft_reg<3>(z);
  twiddle_chain(z, w64);
  SB();
  #pragma unroll
  for (int K2 = 0; K2 < 8; ++K2) seg[((K2 * 8 + ul) ^ x9) + b64] = z[K2]; // L2
  SB();
  // step 3: FFT8 over g1 -> Z[wq + 8ul + 64K1]
  #pragma unroll
  for (int gg = 0; gg < 8; ++gg) z[BR3[gg]] = seg[((ul * 8 + gg) ^ x9) + b64];
  fft_reg<3>(z);
  SB();
  #pragma unroll
  for (int K1 = 0; K1 < 8; ++K1)
    seg[((wq + 8 * ul) ^ (9 * K1)) + 64 * K1] = z[K1];                    // Z natural, swizzled
  SB();
  // Hermitian unpack (fp32) + bf16 pack; stash as uints in own segment.
  unsigned p0[4], p1[4];
  #pragma unroll
  for (int e = 0; e < 4; ++e) {
    int k = u + 64 * e;
    int km = (512 - k) & 511;
    float2 zk = seg[PH(k)];
    float2 zm = seg[PH(km)];
    p0[e] = bfpack(make_float2(0.5f * (zk.x + zm.x),  0.5f * (zk.y - zm.y)));
    p1[e] = bfpack(make_float2(0.5f * (zk.y + zm.y), -0.5f * (zk.x - zm.x)));
  }
  unsigned p0n = 0, p1n = 0;
  if (u == 0) {
    float2 zk = seg[PH(256)];            // Nyquist (self-paired)
    p0n = bfpack(make_float2(zk.x, 0.0f));
    p1n = bfpack(make_float2(zk.y, 0.0f));
  }
  SB();
  #pragma unroll
  for (int e = 0; e < 4; ++e) {
    int k = u + 64 * e;
    useg[k] = p0[e];                     // row 2rp   spectrum at [k]
    useg[257 + k] = p1[e];               // row 2rp+1 spectrum at [257+k]
  }
  if (u == 0) { useg[256] = p0n; useg[513] = p1n; }
  __syncthreads();

  // transposed write-out: for each j, 32 consecutive i (128B run).
  unsigned* FTc = FT + (size_t)ic_local * (W2 * FTS);
  int i0 = segblk * 32;
  const unsigned* xb = (const unsigned*)xbuf;
  #pragma unroll
  for (int it = 0; it < 9; ++it) {
    int idx = t + TPB1 * it;
    if (idx < W2 * 32) {
      int j = idx >> 5;
      int il = idx & 31;                 // i_local = 2*pair + hi
      unsigned v = xb[(il >> 1) * CSU + (il & 1) * 257 + j];
      FTc[(size_t)j * FTS + i0 + il] = v;
    }
  }
}

// Pass 2: blockIdx.x = b_local*NTILE + tile. Wave wv owns column j = tile*4+wv.
// Contiguous 2KB column loads; wave-private bf16 FFT; zero staging barriers.
__global__ __launch_bounds__(TPB2, 4) void pass2_kernel(
    const unsigned* __restrict__ FT, const unsigned char* __restrict__ binsT,
    float* __restrict__ partial, int b0) {
  __shared__ unsigned xbuf[4 * CSB];     // 8.2 KB: 4 wave-private segments
  __shared__ float hist[128];            // combined bins: rb + 16*ob
  int t = threadIdx.x;
  int tile = blockIdx.x % NTILE;
  int b_local = blockIdx.x / NTILE;
  int wv = t >> 6;
  int u = t & 63;
  int j = tile * 4 + wv;
  bool jvalid = (j < W2);
  unsigned* seg = xbuf + wv * CSB;
  const int ul = u & 7, wq = u >> 3;
  const int x9 = 9 * wq, b64 = 64 * wq;

  if (t < 128) hist[t] = 0.0f;
  __syncthreads();

  if (jvalid) {
    float2 w1, w64;
    { float sn, cs;
      sincosf(-TWO_PI_F * (float)u * (1.0f / 512.0f), &sn, &cs);  w1  = make_float2(cs, sn);
      sincosf(-TWO_PI_F * (float)ul * (1.0f / 64.0f), &sn, &cs);  w64 = make_float2(cs, sn); }

    float mag[8];
    #pragma unroll
    for (int q = 0; q < 8; ++q) mag[q] = 0.0f;

    for (int c = 0; c < 3; ++c) {
      const unsigned* col = FT + ((size_t)(b_local * 3 + c) * W2 + j) * FTS;
      float2 z[8];
      #pragma unroll
      for (int m = 0; m < 8; ++m) z[BR3[m]] = bfunpack(col[u + 64 * m]);
      fft_reg<3>(z);
      twiddle_chain(z, w1);
      SB();
      #pragma unroll
      for (int k3 = 0; k3 < 8; ++k3) seg[(u ^ (9 * k3)) + 64 * k3] = bfpack(z[k3]);
      SB();
      #pragma unroll
      for (int g2 = 0; g2 < 8; ++g2) z[BR3[g2]] = bfunpack(seg[((ul + 8 * g2) ^ x9) + b64]);
      fft_reg<3>(z);
      twiddle_chain(z, w64);
      SB();
      #pragma unroll
      for (int K2 = 0; K2 < 8; ++K2) seg[((K2 * 8 + ul) ^ x9) + b64] = bfpack(z[K2]);
      SB();
      #pragma unroll
      for (int gg = 0; gg < 8; ++gg) z[BR3[gg]] = bfunpack(seg[((ul * 8 + gg) ^ x9) + b64]);
      fft_reg<3>(z);
      #pragma unroll
      for (int K1 = 0; K1 < 8; ++K1)
        mag[K1] += sqrtf(z[K1].x * z[K1].x + z[K1].y * z[K1].y);
      SB();                              // seg reads done before next channel's writes
    }

    const unsigned char* bj = binsT + (size_t)j * 512;
    #pragma unroll
    for (int K1 = 0; K1 < 8; ++K1) {
      int row = wq + 8 * ul + 64 * K1;
      int code = bj[row];                // coalesced 64B run per K1
      // scale: ortho (1/512) * channel mean (1/3) = 1/1536
      atomicAdd(&hist[code], log1pf(mag[K1] * (1.0f / 1536.0f)));
    }
  }
  __syncthreads();

  // fold 128 combined bins -> 16 radial + 8 angular partials
  int b = b0 + b_local;
  if (t < 16) {
    float s = 0.0f;
    #pragma unroll
    for (int ob = 0; ob < 8; ++ob) s += hist[t + 16 * ob];
    partial[((size_t)b * NTILE + tile) * 24 + t] = s;
  } else if (t < 24) {
    float s = 0.0f;
    int ob = t - 16;
    #pragma unroll
    for (int rb = 0; rb < 16; ++rb) s += hist[rb + 16 * ob];
    partial[((size_t)b * NTILE + tile) * 24 + t] = s;
  }
}

// Pass 3: one block per batch. Reduce NTILE partials, normalize, project.
__global__ __launch_bounds__(TPB0) void pass3_kernel(
    const float* __restrict__ partial, const float* __restrict__ W,
    const float* __restrict__ bias, float* __restrict__ out) {
  __shared__ float h[24];
  __shared__ float hn[24];
  int b = blockIdx.x;
  int t = threadIdx.x;
  if (t < 24) {
    float s = 0.0f;
    for (int tile = 0; tile < NTILE; tile++)
      s += partial[((size_t)b * NTILE + tile) * 24 + t];
    h[t] = s;
  }
  __syncthreads();
  if (t == 0) {
    float rs = 0.0f, as = 0.0f;
    for (int k = 0; k < 16; k++) rs += h[k];
    for (int k = 16; k < 24; k++) as += h[k];
    for (int k = 0; k < 16; k++) hn[k] = h[k] / (rs + 1e-6f);
    for (int k = 16; k < 24; k++) hn[k] = h[k] / (as + 1e-6f);
  }
  __syncthreads();
  if (t < 64) {
    float acc = bias[t];
    #pragma unroll
    for (int k = 0; k < 24; k++) acc += hn[k] * W[t * 24 + k];
    out[b * 64 + t] = acc;
  }
}

extern "C" void kernel_launch(void* const* d_in, const int* in_sizes, int n_in,
                              void* d_out, int out_size, void* d_ws, size_t ws_size,
                              hipStream_t stream) {
  const float* x    = (const float*)d_in[0];   // [64,3,512,512]
  const float* W    = (const float*)d_in[1];   // [64,24]
  const float* bias = (const float*)d_in[2];   // [64]
  float* out = (float*)d_out;                  // [64,64]

  // ws layout: partial hists | transposed bin table | bf16 F^T intermediate
  const size_t partial_bytes = (size_t)64 * NTILE * 24 * sizeof(float);
  size_t off_bins = (partial_bytes + 255) & ~(size_t)255;
  const size_t bins_bytes = (size_t)W2 * 512;
  size_t off_F = ((off_bins + bins_bytes) + 255) & ~(size_t)255;

  float* partial = (float*)d_ws;
  unsigned char* binsT = (unsigned char*)d_ws + off_bins;
  unsigned* FT = (unsigned*)((char*)d_ws + off_F);

  const size_t per_batch = (size_t)3 * W2 * FTS * sizeof(unsigned);  // 1.58 MB
  size_t avail = ws_size > off_F ? ws_size - off_F : 0;
  int bpc = (int)(avail / per_batch);
  if (bpc < 1) bpc = 1;
  if (bpc > 64) bpc = 64;

  pass0_kernel<<<W2, TPB0, 0, stream>>>(binsT);

  for (int b0 = 0; b0 < 64; b0 += bpc) {
    int nb = (64 - b0) < bpc ? (64 - b0) : bpc;
    pass1_kernel<<<nb * 3 * 16, TPB1, 0, stream>>>(x, FT, b0 * 3);
    pass2_kernel<<<nb * NTILE, TPB2, 0, stream>>>(FT, binsT, partial, b0);
  }
  pass3_kernel<<<64, TPB0, 0, stream>>>(partial, W, bias, out);
}